// Round 6
// baseline (296.648 us; speedup 1.0000x reference)
//
#include <hip/hip_runtime.h>

// DiffTreeInterpreter: row-pair CSR gather, inline-asm batched-load edition.
//
// Output row r (batch b):
//   half: r<2048: car from role 2r (scale op0*w0), cdr from role 2r+1>=3 (op1*w1)
//   cons: all r: from role r>>1 (scale op2*w2 if r even else op2*w3)
//   root: out[b,1,:] += op2*root_filler[b]
// One wave handles the row PAIR (2q, 2q+1).
//
// R0-R5 post-mortem: every IR-level attempt (launch_bounds, sched_barrier,
// KEEP asm anchors) left VGPR_Count=48 and dur=85us -- the compiler always
// finds a legal low-pressure schedule that serializes load->wait->FMA
// (wave lifetime 11.5k cy ~= 13 x ~850cy serial loads; logical traffic only
// ~3.9 TB/s, no service wall). R6: the 20 row loads are inline-asm volatile
// global_load_dwordx2 (mutually ordered, no compiler waitcnt) followed by ONE
// asm s_waitcnt vmcnt(0) that redefines all 20 destinations ("+v") ->
// back-to-back issue and a single drain are now guaranteed at the ISA level.
// Invalid slots load row 0 (all-zero, L1-resident) with scale 0 - numerics
// unchanged; guard branches eliminated.

namespace {
constexpr int kB = 32;
constexpr int kL = 128;
constexpr int kF = 128;
constexpr int kR = 4096;
constexpr int kN = 262144;
constexpr int kQ = 2048;       // row-pairs per batch == half-rows per batch
constexpr int kNP = kB * kQ;   // 65536 keys
constexpr int kCap = 16;       // entries per record; P(Poisson(4)>16)~4e-7
constexpr int kOvfMax = 65536;

// workspace layout (bytes)
constexpr size_t kOffRowCnt  = 0;        // kNP*4  = 262144
constexpr size_t kOffConsCnt = 262144;   // kNP*4  = 262144
constexpr size_t kOffOvfCnt  = 524288;   // 4 (pad 16)
constexpr size_t kOffOvf     = 524304;   // kOvfMax*16 = 1048576
constexpr size_t kOffRowEnt  = 1572880;  // kNP*kCap*8  = 8388608  (int2)
constexpr size_t kOffConsEnt = 9961488;  // kNP*kCap*16 = 16777216 (int4)
// end: 26,738,704 bytes (~25.5 MB)
}  // namespace

typedef float __attribute__((ext_vector_type(2))) f32x2;

__global__ __launch_bounds__(256) void build_kernel(
    const float4* __restrict__ aw, const float* __restrict__ opd,
    const int* __restrict__ bidx, const int* __restrict__ sidx,
    const int* __restrict__ ridx,
    int* __restrict__ rowcnt, int* __restrict__ conscnt,
    int* __restrict__ ovf_cnt, int4* __restrict__ ovf,
    int2* __restrict__ rowent, int4* __restrict__ consent) {
  int n = blockIdx.x * 256 + threadIdx.x;
  if (n >= kN) return;
  int b = bidx[n];
  int s = sidx[n];
  int rr = ridx[n];
  float4 w = aw[b * kL + s];
  float op0 = opd[3 * b + 0];
  float op1 = opd[3 * b + 1];
  float op2 = opd[3 * b + 2];

  // half contribution -> row rr>>1 (car if even, cdr if odd>=3; role 1 dropped)
  bool even = (rr & 1) == 0;
  if (even || rr >= 3) {
    float sc = even ? op0 * w.x : op1 * w.y;
    int key = (b << 11) | (rr >> 1);
    int pos = atomicAdd(&rowcnt[key], 1);
    if (pos < kCap) {
      rowent[key * kCap + pos] = make_int2(n, __float_as_int(sc));
    } else {
      int o = atomicAdd(ovf_cnt, 1);
      if (o < kOvfMax)
        ovf[o] = make_int4(b * kR + (rr >> 1), n, __float_as_int(sc), 0);
    }
  }
  // cons contribution -> rows 2rr, 2rr+1 : ONE entry (n, s1, s2)
  if (rr < kQ) {
    int key = (b << 11) | rr;
    int pos = atomicAdd(&conscnt[key], 1);
    if (pos < kCap) {
      consent[key * kCap + pos] =
          make_int4(n, __float_as_int(op2 * w.z), __float_as_int(op2 * w.w), 0);
    } else {
      int o = atomicAdd(ovf_cnt, 2);
      if (o < kOvfMax)
        ovf[o] = make_int4(b * kR + 2 * rr, n, __float_as_int(op2 * w.z), 0);
      if (o + 1 < kOvfMax)
        ovf[o + 1] =
            make_int4(b * kR + 2 * rr + 1, n, __float_as_int(op2 * w.w), 0);
    }
  }
}

// Inline-asm 8B load: volatile => ordered with other asm, never re-scheduled,
// no compiler-inserted waitcnt (we drain manually, once).
#define GLOAD(dst, a64) \
  asm volatile("global_load_dwordx2 %0, %1, off" : "=v"(dst) : "v"(a64))

// launch_bounds(256,4): VGPR cap 128; the 20-pair in-flight buffer needs it.
__global__ __launch_bounds__(256, 4) void gather_kernel(
    const float2* __restrict__ mem2, const float2* __restrict__ root2,
    const float* __restrict__ opd,
    const int* __restrict__ rowcnt, const int* __restrict__ conscnt,
    const int2* __restrict__ rowent, const int2* __restrict__ consent2,
    float2* __restrict__ out2) {
  const int p = blockIdx.x * 4 + (threadIdx.x >> 6);  // pair id = (b<<11)|q
  const int t = threadIdx.x & 63;                     // lane: features 2t,2t+1
  const int b = p >> 11;
  const int q = p & (kQ - 1);
  const bool hashalf = q < 1024;  // rows 2q,2q+1 < 2048

  // ---- round 1: ALL structure loads, fully independent ----
  int cn_raw = conscnt[p];
  int2 ce = make_int2(0, 0);
  if (t < 32) ce = (consent2 + (size_t)p * 2 * kCap)[t];  // 16 int4 = 32 int2
  int2 hc = make_int2(0, 0);
  int2 he = make_int2(0, 0);
  if (hashalf) {
    int key0 = (b << 11) | (q << 1);            // even -> 8B aligned
    hc = *(const int2*)(rowcnt + key0);         // counts for rows 2q, 2q+1
    if (t < 32) he = (rowent + (size_t)key0 * kCap)[t];  // both records, 256B
  }
  int cn = min(__builtin_amdgcn_readfirstlane(cn_raw), kCap);
  int h0 = 0, h1 = 0;
  if (hashalf) {
    h0 = min(__builtin_amdgcn_readfirstlane(hc.x), kCap);
    h1 = min(__builtin_amdgcn_readfirstlane(hc.y), kCap);
  }

  // ---- round 2: branchless address calc + 20 batched asm loads ----
  // Invalid slots -> row 0 (all-zero in this dataset, L1-resident), scale 0.
  const uint64_t membase = (uint64_t)(const void*)mem2 + (uint64_t)(t << 3);

  int ncn[4];
  float c1s[4], c2s[4];
#pragma unroll
  for (int j = 0; j < 4; ++j) {
    bool v = j < cn;
    int nn = __shfl(ce.x, 2 * j);
    float a = __int_as_float(__shfl(ce.y, 2 * j));
    float bb = __int_as_float(__shfl(ce.x, 2 * j + 1));
    ncn[j] = v ? nn : 0;  // slots >= cn hold 0xAA poison
    c1s[j] = v ? a : 0.f;
    c2s[j] = v ? bb : 0.f;
  }
  int nh0[8], nh1[8];
  float s0a[8], s1a[8];
#pragma unroll
  for (int j = 0; j < 8; ++j) {
    bool v0 = j < h0;
    int n0 = __shfl(he.x, j);
    float s0 = __int_as_float(__shfl(he.y, j));
    nh0[j] = v0 ? n0 : 0;
    s0a[j] = v0 ? s0 : 0.f;
    bool v1 = j < h1;
    int n1 = __shfl(he.x, 16 + j);
    float s1 = __int_as_float(__shfl(he.y, 16 + j));
    nh1[j] = v1 ? n1 : 0;
    s1a[j] = v1 ? s1 : 0.f;
  }

  f32x2 mc[4], m0[8], m1[8];
#pragma unroll
  for (int j = 0; j < 4; ++j)
    GLOAD(mc[j], membase + ((uint64_t)(uint32_t)ncn[j] << 9));
#pragma unroll
  for (int j = 0; j < 8; ++j)
    GLOAD(m0[j], membase + ((uint64_t)(uint32_t)nh0[j] << 9));
#pragma unroll
  for (int j = 0; j < 8; ++j)
    GLOAD(m1[j], membase + ((uint64_t)(uint32_t)nh1[j] << 9));

  // ---- ONE drain; "+v" on every destination makes all consumers
  // data-dependent on the post-wait values (cannot be hoisted above).
  asm volatile("s_waitcnt vmcnt(0)"
               : "+v"(mc[0]), "+v"(mc[1]), "+v"(mc[2]), "+v"(mc[3]),
                 "+v"(m0[0]), "+v"(m0[1]), "+v"(m0[2]), "+v"(m0[3]),
                 "+v"(m0[4]), "+v"(m0[5]), "+v"(m0[6]), "+v"(m0[7]),
                 "+v"(m1[0]), "+v"(m1[1]), "+v"(m1[2]), "+v"(m1[3]),
                 "+v"(m1[4]), "+v"(m1[5]), "+v"(m1[6]), "+v"(m1[7])
               :
               : "memory");
  __builtin_amdgcn_sched_barrier(0);  // rule #18: nothing crosses the wait

  // ---- accumulate ----
  float ax0 = 0.f, ay0 = 0.f, ax1 = 0.f, ay1 = 0.f;
#pragma unroll
  for (int j = 0; j < 4; ++j) {
    ax0 += c1s[j] * mc[j][0];
    ay0 += c1s[j] * mc[j][1];
    ax1 += c2s[j] * mc[j][0];
    ay1 += c2s[j] * mc[j][1];
  }
#pragma unroll
  for (int j = 0; j < 8; ++j) {
    ax0 += s0a[j] * m0[j][0];
    ay0 += s0a[j] * m0[j][1];
  }
#pragma unroll
  for (int j = 0; j < 8; ++j) {
    ax1 += s1a[j] * m1[j][0];
    ay1 += s1a[j] * m1[j][1];
  }

  // ---- rare tails (compiler loads; drained region, counts are correct) ----
  for (int i = 4; i < cn; i += 4) {
#pragma unroll
    for (int j = 0; j < 4; ++j) {
      int idx = i + j;
      bool v = idx < cn;
      int nn = __shfl(ce.x, 2 * idx);
      float a = __int_as_float(__shfl(ce.y, 2 * idx));
      float bb = __int_as_float(__shfl(ce.x, 2 * idx + 1));
      nn = v ? nn : 0;
      a = v ? a : 0.f;
      bb = v ? bb : 0.f;
      float2 m = mem2[(size_t)nn * (kF / 2) + t];
      ax0 += a * m.x;
      ay0 += a * m.y;
      ax1 += bb * m.x;
      ay1 += bb * m.y;
    }
  }
  for (int i = 8; i < h0; i += 4) {
#pragma unroll
    for (int j = 0; j < 4; ++j) {
      int idx = i + j;
      bool v = idx < h0;
      int nn = __shfl(he.x, idx);
      float s = __int_as_float(__shfl(he.y, idx));
      nn = v ? nn : 0;
      s = v ? s : 0.f;
      float2 m = mem2[(size_t)nn * (kF / 2) + t];
      ax0 += s * m.x;
      ay0 += s * m.y;
    }
  }
  for (int i = 8; i < h1; i += 4) {
#pragma unroll
    for (int j = 0; j < 4; ++j) {
      int idx = i + j;
      bool v = idx < h1;
      int nn = __shfl(he.x, 16 + idx);
      float s = __int_as_float(__shfl(he.y, 16 + idx));
      nn = v ? nn : 0;
      s = v ? s : 0.f;
      float2 m = mem2[(size_t)nn * (kF / 2) + t];
      ax1 += s * m.x;
      ay1 += s * m.y;
    }
  }

  // ---- root filler (row 1 <=> q==0) + writeback ----
  if (q == 0) {
    float op2 = opd[3 * b + 2];
    float2 rf = root2[b * (kF / 2) + t];
    ax1 += op2 * rf.x;
    ay1 += op2 * rf.y;
  }
  size_t orow = ((size_t)b * kR + 2 * q) * (kF / 2) + t;
  out2[orow] = make_float2(ax0, ay0);
  out2[orow + (kF / 2)] = make_float2(ax1, ay1);
}

// Overflow fallback (expected ~0 entries): direct atomic add.
// Must run AFTER gather_kernel (gather writes out with '=').
__global__ __launch_bounds__(128) void ovf_kernel(
    const float* __restrict__ mem, const int* __restrict__ ovf_cnt,
    const int4* __restrict__ ovf, float* __restrict__ out) {
  int m = *ovf_cnt;
  if (m > kOvfMax) m = kOvfMax;
  const int t = threadIdx.x;  // feature 0..127
  for (int i = blockIdx.x; i < m; i += gridDim.x) {
    int4 e = ovf[i];
    float sc = __int_as_float(e.z);
    atomicAdd(&out[(size_t)e.x * kF + t], sc * mem[(size_t)e.y * kF + t]);
  }
}

extern "C" void kernel_launch(void* const* d_in, const int* in_sizes, int n_in,
                              void* d_out, int out_size, void* d_ws, size_t ws_size,
                              hipStream_t stream) {
  const float* mem   = (const float*)d_in[0];   // (N, F)
  const float* aw    = (const float*)d_in[1];   // (B, L, 4)
  const float* rootf = (const float*)d_in[2];   // (B, F)
  const float* opd   = (const float*)d_in[3];   // (B, 3)
  const int* bidx    = (const int*)d_in[4];     // (N,)
  const int* sidx    = (const int*)d_in[5];     // (N,)
  const int* ridx    = (const int*)d_in[6];     // (N,)

  char* ws = (char*)d_ws;
  int* rowcnt   = (int*)(ws + kOffRowCnt);
  int* conscnt  = (int*)(ws + kOffConsCnt);
  int* ovf_cnt  = (int*)(ws + kOffOvfCnt);
  int4* ovf     = (int4*)(ws + kOffOvf);
  int2* rowent  = (int2*)(ws + kOffRowEnt);
  int4* consent = (int4*)(ws + kOffConsEnt);

  // zero all counters in one contiguous memset (ws is poisoned 0xAA each call)
  hipMemsetAsync(ws, 0, kOffOvfCnt + 16, stream);

  build_kernel<<<kN / 256, 256, 0, stream>>>(
      (const float4*)aw, opd, bidx, sidx, ridx, rowcnt, conscnt, ovf_cnt, ovf,
      rowent, consent);

  // 4 pairs per 256-thread block (4 waves x 1 pair) -> 16384 blocks.
  gather_kernel<<<kNP / 4, 256, 0, stream>>>(
      (const float2*)mem, (const float2*)rootf, opd, rowcnt, conscnt, rowent,
      (const int2*)consent, (float2*)d_out);

  ovf_kernel<<<64, 128, 0, stream>>>(mem, ovf_cnt, ovf, (float*)d_out);
}

// Round 7
// 266.177 us; speedup vs baseline: 1.1145x; 1.1145x over previous
//
#include <hip/hip_runtime.h>

// DiffTreeInterpreter: row-pair CSR gather, 2-latency-round edition + NT cache
// policy.
//
// Output row r (batch b):
//   half: r<2048: car from role 2r (scale op0*w0), cdr from role 2r+1>=3 (op1*w1)
//   cons: all r: from role r>>1 (scale op2*w2 if r even else op2*w3)
//   root: out[b,1,:] += op2*root_filler[b]
// One wave handles the row PAIR (2q, 2q+1).
//
// R0-R6 history: schedule-side levers are exhausted and falsified --
//   R1 4-pair/wave: regressed (compiler re-serialized; occupancy loss)
//   R2 16-wave blocks: regressed (packing)
//   R3 launch_bounds(,4), R4 sched_barrier, R5 asm KEEP anchors: no-ops
//   R6 inline-asm batched loads: MLP=20 PROVEN in flight, perf WORSE ->
//      concurrency is NOT the constraint; random-512B service rate is.
// Byte audit: genuine row pulls ~201MB but FETCH_SIZE=107MB -> ~47% of row
// reads MISS the 256MB LLC (mem 128MB + out 64MB write-allocate + structure
// 26MB oversubscribe it) and pay HBM latency. R7: non-temporal stores for out
// (write-once, read-never) and non-temporal loads for structure records
// (read-exactly-once) so the LLC keeps mem_values. Compute structure is the
// measured-best R0 form, untouched.

namespace {
constexpr int kB = 32;
constexpr int kL = 128;
constexpr int kF = 128;
constexpr int kR = 4096;
constexpr int kN = 262144;
constexpr int kQ = 2048;       // row-pairs per batch == half-rows per batch
constexpr int kNP = kB * kQ;   // 65536 keys
constexpr int kCap = 16;       // entries per record; P(Poisson(4)>16)~4e-7
constexpr int kOvfMax = 65536;

// workspace layout (bytes)
constexpr size_t kOffRowCnt  = 0;        // kNP*4  = 262144
constexpr size_t kOffConsCnt = 262144;   // kNP*4  = 262144
constexpr size_t kOffOvfCnt  = 524288;   // 4 (pad 16)
constexpr size_t kOffOvf     = 524304;   // kOvfMax*16 = 1048576
constexpr size_t kOffRowEnt  = 1572880;  // kNP*kCap*8  = 8388608  (int2)
constexpr size_t kOffConsEnt = 9961488;  // kNP*kCap*16 = 16777216 (int4)
// end: 26,738,704 bytes (~25.5 MB)
}  // namespace

typedef int   __attribute__((ext_vector_type(2))) i32x2;
typedef float __attribute__((ext_vector_type(2))) f32x2;

__global__ __launch_bounds__(256) void build_kernel(
    const float4* __restrict__ aw, const float* __restrict__ opd,
    const int* __restrict__ bidx, const int* __restrict__ sidx,
    const int* __restrict__ ridx,
    int* __restrict__ rowcnt, int* __restrict__ conscnt,
    int* __restrict__ ovf_cnt, int4* __restrict__ ovf,
    int2* __restrict__ rowent, int4* __restrict__ consent) {
  int n = blockIdx.x * 256 + threadIdx.x;
  if (n >= kN) return;
  int b = bidx[n];
  int s = sidx[n];
  int rr = ridx[n];
  float4 w = aw[b * kL + s];
  float op0 = opd[3 * b + 0];
  float op1 = opd[3 * b + 1];
  float op2 = opd[3 * b + 2];

  // half contribution -> row rr>>1 (car if even, cdr if odd>=3; role 1 dropped)
  bool even = (rr & 1) == 0;
  if (even || rr >= 3) {
    float sc = even ? op0 * w.x : op1 * w.y;
    int key = (b << 11) | (rr >> 1);
    int pos = atomicAdd(&rowcnt[key], 1);
    if (pos < kCap) {
      rowent[key * kCap + pos] = make_int2(n, __float_as_int(sc));
    } else {
      int o = atomicAdd(ovf_cnt, 1);
      if (o < kOvfMax)
        ovf[o] = make_int4(b * kR + (rr >> 1), n, __float_as_int(sc), 0);
    }
  }
  // cons contribution -> rows 2rr, 2rr+1 : ONE entry (n, s1, s2)
  if (rr < kQ) {
    int key = (b << 11) | rr;
    int pos = atomicAdd(&conscnt[key], 1);
    if (pos < kCap) {
      consent[key * kCap + pos] =
          make_int4(n, __float_as_int(op2 * w.z), __float_as_int(op2 * w.w), 0);
    } else {
      int o = atomicAdd(ovf_cnt, 2);
      if (o < kOvfMax)
        ovf[o] = make_int4(b * kR + 2 * rr, n, __float_as_int(op2 * w.z), 0);
      if (o + 1 < kOvfMax)
        ovf[o + 1] =
            make_int4(b * kR + 2 * rr + 1, n, __float_as_int(op2 * w.w), 0);
    }
  }
}

__global__ __launch_bounds__(256) void gather_kernel(
    const float2* __restrict__ mem2, const float2* __restrict__ root2,
    const float* __restrict__ opd,
    const int* __restrict__ rowcnt, const int* __restrict__ conscnt,
    const int2* __restrict__ rowent, const int2* __restrict__ consent2,
    float2* __restrict__ out2) {
  const int p = blockIdx.x * 4 + (threadIdx.x >> 6);  // pair id = (b<<11)|q
  const int t = threadIdx.x & 63;                     // lane: features 2t,2t+1
  const int b = p >> 11;
  const int q = p & (kQ - 1);
  const bool hashalf = q < 1024;  // rows 2q,2q+1 < 2048

  // ---- round 1: ALL structure loads, fully independent ----
  // NT loads: every record/count is read exactly once across the whole
  // dispatch -> evict-first, keep LLC capacity for mem_values.
  int cn_raw = __builtin_nontemporal_load(conscnt + p);
  i32x2 ce = (i32x2)0;
  if (t < 32)
    ce = __builtin_nontemporal_load(
        (const i32x2*)(consent2 + (size_t)p * 2 * kCap) + t);
  i32x2 hc = (i32x2)0;
  i32x2 he = (i32x2)0;
  if (hashalf) {
    int key0 = (b << 11) | (q << 1);  // even -> 8B aligned
    hc = __builtin_nontemporal_load((const i32x2*)(rowcnt + key0));
    if (t < 32)
      he = __builtin_nontemporal_load(
          (const i32x2*)(rowent + (size_t)key0 * kCap) + t);
  }
  int cn = min(__builtin_amdgcn_readfirstlane(cn_raw), kCap);
  int h0 = 0, h1 = 0;
  if (hashalf) {
    h0 = min(__builtin_amdgcn_readfirstlane(hc.x), kCap);
    h1 = min(__builtin_amdgcn_readfirstlane(hc.y), kCap);
  }

  // ---- round 2: issue phase (all mem-row loads independent) ----
  // cons: width 4 (P(Poisson(2)>4)=5% -> tail loop)
  float2 mc[4];
  float c1s[4], c2s[4];
#pragma unroll
  for (int j = 0; j < 4; ++j) {
    c1s[j] = 0.f;
    c2s[j] = 0.f;
    mc[j] = make_float2(0.f, 0.f);
  }
  if (cn > 0) {
#pragma unroll
    for (int j = 0; j < 4; ++j) {
      bool v = j < cn;
      int nn = __shfl(ce.x, 2 * j);
      float a = __int_as_float(__shfl(ce.y, 2 * j));
      float bb = __int_as_float(__shfl(ce.x, 2 * j + 1));
      nn = v ? nn : 0;  // slots >= cn hold 0xAA poison
      c1s[j] = v ? a : 0.f;
      c2s[j] = v ? bb : 0.f;
      mc[j] = mem2[(size_t)nn * (kF / 2) + t];
    }
  }
  // halves: width 8 (P(Poisson(4)>8)=2% -> tail loop)
  float2 m0[8], m1[8];
  float s0a[8], s1a[8];
#pragma unroll
  for (int j = 0; j < 8; ++j) {
    s0a[j] = 0.f;
    s1a[j] = 0.f;
    m0[j] = make_float2(0.f, 0.f);
    m1[j] = make_float2(0.f, 0.f);
  }
  if (h0 > 0) {
#pragma unroll
    for (int j = 0; j < 4; ++j) {
      bool v = j < h0;
      int nn = __shfl(he.x, j);
      float s = __int_as_float(__shfl(he.y, j));
      nn = v ? nn : 0;
      s0a[j] = v ? s : 0.f;
      m0[j] = mem2[(size_t)nn * (kF / 2) + t];
    }
    if (h0 > 4) {
#pragma unroll
      for (int j = 4; j < 8; ++j) {
        bool v = j < h0;
        int nn = __shfl(he.x, j);
        float s = __int_as_float(__shfl(he.y, j));
        nn = v ? nn : 0;
        s0a[j] = v ? s : 0.f;
        m0[j] = mem2[(size_t)nn * (kF / 2) + t];
      }
    }
  }
  if (h1 > 0) {
#pragma unroll
    for (int j = 0; j < 4; ++j) {
      bool v = j < h1;
      int nn = __shfl(he.x, 16 + j);
      float s = __int_as_float(__shfl(he.y, 16 + j));
      nn = v ? nn : 0;
      s1a[j] = v ? s : 0.f;
      m1[j] = mem2[(size_t)nn * (kF / 2) + t];
    }
    if (h1 > 4) {
#pragma unroll
      for (int j = 4; j < 8; ++j) {
        bool v = j < h1;
        int nn = __shfl(he.x, 16 + j);
        float s = __int_as_float(__shfl(he.y, 16 + j));
        nn = v ? nn : 0;
        s1a[j] = v ? s : 0.f;
        m1[j] = mem2[(size_t)nn * (kF / 2) + t];
      }
    }
  }

  // ---- accumulate ----
  float ax0 = 0.f, ay0 = 0.f, ax1 = 0.f, ay1 = 0.f;
#pragma unroll
  for (int j = 0; j < 4; ++j) {
    ax0 += c1s[j] * mc[j].x;
    ay0 += c1s[j] * mc[j].y;
    ax1 += c2s[j] * mc[j].x;
    ay1 += c2s[j] * mc[j].y;
  }
#pragma unroll
  for (int j = 0; j < 8; ++j) {
    ax0 += s0a[j] * m0[j].x;
    ay0 += s0a[j] * m0[j].y;
  }
#pragma unroll
  for (int j = 0; j < 8; ++j) {
    ax1 += s1a[j] * m1[j].x;
    ay1 += s1a[j] * m1[j].y;
  }

  // ---- rare tails ----
  for (int i = 4; i < cn; i += 4) {
#pragma unroll
    for (int j = 0; j < 4; ++j) {
      int idx = i + j;
      bool v = idx < cn;
      int nn = __shfl(ce.x, 2 * idx);
      float a = __int_as_float(__shfl(ce.y, 2 * idx));
      float bb = __int_as_float(__shfl(ce.x, 2 * idx + 1));
      nn = v ? nn : 0;
      a = v ? a : 0.f;
      bb = v ? bb : 0.f;
      float2 m = mem2[(size_t)nn * (kF / 2) + t];
      ax0 += a * m.x;
      ay0 += a * m.y;
      ax1 += bb * m.x;
      ay1 += bb * m.y;
    }
  }
  for (int i = 8; i < h0; i += 4) {
#pragma unroll
    for (int j = 0; j < 4; ++j) {
      int idx = i + j;
      bool v = idx < h0;
      int nn = __shfl(he.x, idx);
      float s = __int_as_float(__shfl(he.y, idx));
      nn = v ? nn : 0;
      s = v ? s : 0.f;
      float2 m = mem2[(size_t)nn * (kF / 2) + t];
      ax0 += s * m.x;
      ay0 += s * m.y;
    }
  }
  for (int i = 8; i < h1; i += 4) {
#pragma unroll
    for (int j = 0; j < 4; ++j) {
      int idx = i + j;
      bool v = idx < h1;
      int nn = __shfl(he.x, 16 + idx);
      float s = __int_as_float(__shfl(he.y, 16 + idx));
      nn = v ? nn : 0;
      s = v ? s : 0.f;
      float2 m = mem2[(size_t)nn * (kF / 2) + t];
      ax1 += s * m.x;
      ay1 += s * m.y;
    }
  }

  // ---- root filler (row 1 <=> q==0) + writeback ----
  if (q == 0) {
    float op2 = opd[3 * b + 2];
    float2 rf = root2[b * (kF / 2) + t];
    ax1 += op2 * rf.x;
    ay1 += op2 * rf.y;
  }
  // NT stores: out is write-once / read-never -> do not allocate 64MB of LLC
  // (write-allocate of out lines is what evicts mem_values rows).
  size_t orow = ((size_t)b * kR + 2 * q) * (kF / 2) + t;
  f32x2 o0;
  o0.x = ax0;
  o0.y = ay0;
  f32x2 o1;
  o1.x = ax1;
  o1.y = ay1;
  __builtin_nontemporal_store(o0, (f32x2*)(out2 + orow));
  __builtin_nontemporal_store(o1, (f32x2*)(out2 + orow + (kF / 2)));
}

// Overflow fallback (expected ~0 entries): direct atomic add.
// Must run AFTER gather_kernel (gather writes out with '=').
__global__ __launch_bounds__(128) void ovf_kernel(
    const float* __restrict__ mem, const int* __restrict__ ovf_cnt,
    const int4* __restrict__ ovf, float* __restrict__ out) {
  int m = *ovf_cnt;
  if (m > kOvfMax) m = kOvfMax;
  const int t = threadIdx.x;  // feature 0..127
  for (int i = blockIdx.x; i < m; i += gridDim.x) {
    int4 e = ovf[i];
    float sc = __int_as_float(e.z);
    atomicAdd(&out[(size_t)e.x * kF + t], sc * mem[(size_t)e.y * kF + t]);
  }
}

extern "C" void kernel_launch(void* const* d_in, const int* in_sizes, int n_in,
                              void* d_out, int out_size, void* d_ws, size_t ws_size,
                              hipStream_t stream) {
  const float* mem   = (const float*)d_in[0];   // (N, F)
  const float* aw    = (const float*)d_in[1];   // (B, L, 4)
  const float* rootf = (const float*)d_in[2];   // (B, F)
  const float* opd   = (const float*)d_in[3];   // (B, 3)
  const int* bidx    = (const int*)d_in[4];     // (N,)
  const int* sidx    = (const int*)d_in[5];     // (N,)
  const int* ridx    = (const int*)d_in[6];     // (N,)

  char* ws = (char*)d_ws;
  int* rowcnt   = (int*)(ws + kOffRowCnt);
  int* conscnt  = (int*)(ws + kOffConsCnt);
  int* ovf_cnt  = (int*)(ws + kOffOvfCnt);
  int4* ovf     = (int4*)(ws + kOffOvf);
  int2* rowent  = (int2*)(ws + kOffRowEnt);
  int4* consent = (int4*)(ws + kOffConsEnt);

  // zero all counters in one contiguous memset (ws is poisoned 0xAA each call)
  hipMemsetAsync(ws, 0, kOffOvfCnt + 16, stream);

  build_kernel<<<kN / 256, 256, 0, stream>>>(
      (const float4*)aw, opd, bidx, sidx, ridx, rowcnt, conscnt, ovf_cnt, ovf,
      rowent, consent);

  // 4 pairs per 256-thread block (4 waves x 1 pair) -> 16384 blocks.
  gather_kernel<<<kNP / 4, 256, 0, stream>>>(
      (const float2*)mem, (const float2*)rootf, opd, rowcnt, conscnt, rowent,
      (const int2*)consent, (float2*)d_out);

  ovf_kernel<<<64, 128, 0, stream>>>(mem, ovf_cnt, ovf, (float*)d_out);
}